// Round 8
// baseline (109.323 us; speedup 1.0000x reference)
//
#include <hip/hip_runtime.h>
#include <math.h>

#define BS    128
#define NE    512
#define F     6
#define NH    4
#define DPH   4
#define NEMBD 16

#define CH    8
#define CPAD  65   // float4 stride/chunk; 8 broadcast addrs per wave -> conflict-free (r2-r7)

#if __has_builtin(__builtin_amdgcn_exp2f)
#define EXP2(x) __builtin_amdgcn_exp2f(x)
#else
#define EXP2(x) exp2f(x)
#endif

typedef float v2f __attribute__((ext_vector_type(2)));

// ---------------------------------------------------------------------------
// Kernel 1: QKV projection + deterministic mask-compaction, ONCE per batch.
// 128 blocks x 512 threads. Active entity t gets slot s (ballot+wave-scan,
// deterministic); writes qc/kc/vc[b][h][s] (coalesced float4), rlist, cnt.
// Pad slots [Nk, 8*ceil(Nk/8)) are zeroed so attn needs no zero-init pass.
// ---------------------------------------------------------------------------
__global__ __launch_bounds__(NE) void qkv_kernel(
    const float* __restrict__ inp, const float* __restrict__ mask,
    const float* __restrict__ Wq, const float* __restrict__ Wk,
    const float* __restrict__ Wv,
    float4* __restrict__ qc, float4* __restrict__ kc, float4* __restrict__ vc,
    unsigned short* __restrict__ rlist, int* __restrict__ cnt)
{
    const int b    = blockIdx.x;
    const int t    = threadIdx.x;
    const int w    = t >> 6;
    const int lane = t & 63;

    __shared__ int wcnt[8];

    const float me = mask[b * NE + t];
    const bool act = me > 0.f;                 // mask is exactly 0.0 or 1.0

    const unsigned long long ball = __ballot(act);
    const int prefix = __builtin_amdgcn_mbcnt_hi((unsigned int)(ball >> 32),
                        __builtin_amdgcn_mbcnt_lo((unsigned int)ball, 0));
    if (lane == 0) wcnt[w] = (int)__popcll(ball);
    __syncthreads();

    int base = 0, Nk = 0;
    #pragma unroll
    for (int u = 0; u < 8; ++u) {
        const int cu = wcnt[u];
        Nk += cu;
        if (u < w) base += cu;
    }
    const int L8 = ((Nk + 7) >> 3) << 3;       // padded slot count

    if (act) {
        const int s = base + prefix;
        const float2* rp = (const float2*)(inp + ((size_t)(b * NE + t)) * F);
        const float2 r0 = rp[0], r1 = rp[1], r2 = rp[2];
        const float x0 = r0.x, x1 = r0.y, x2 = r1.x,
                    x3 = r1.y, x4 = r2.x, x5 = r2.y;   // mask=1: no scaling
        const float QS = 0.5f * 1.44269504088896340736f;  // 1/sqrt(4)*log2(e)
        #pragma unroll
        for (int h = 0; h < NH; ++h) {
            float qq[4], kk[4], vv[4];
            #pragma unroll
            for (int d = 0; d < DPH; ++d) {
                const float* wd = Wq + (h * DPH + d) * F;
                qq[d] = QS * (x0*wd[0] + x1*wd[1] + x2*wd[2] + x3*wd[3] + x4*wd[4] + x5*wd[5]);
                wd = Wk + (h * DPH + d) * F;
                kk[d] = x0*wd[0] + x1*wd[1] + x2*wd[2] + x3*wd[3] + x4*wd[4] + x5*wd[5];
                wd = Wv + (h * DPH + d) * F;
                vv[d] = x0*wd[0] + x1*wd[1] + x2*wd[2] + x3*wd[3] + x4*wd[4] + x5*wd[5];
            }
            const size_t o = (size_t)(b * NH + h) * NE + s;
            qc[o] = make_float4(qq[0], qq[1], qq[2], qq[3]);
            kc[o] = make_float4(kk[0], kk[1], kk[2], kk[3]);
            vc[o] = make_float4(vv[0], vv[1], vv[2], vv[3]);
        }
        rlist[b * NE + s] = (unsigned short)t;
    }

    // zero-pad slots [Nk, L8): thread id == pad slot (<=7 threads; a thread may
    // also be active above -- its active slot is < Nk, disjoint from pad slot)
    if (t >= Nk && t < L8) {
        const float4 z4 = make_float4(0.f, 0.f, 0.f, 0.f);
        #pragma unroll
        for (int h = 0; h < NH; ++h) {
            const size_t o = (size_t)(b * NH + h) * NE + t;
            qc[o] = z4; kc[o] = z4; vc[o] = z4;
        }
    }
    if (t == 0) cnt[b] = Nk;
}

// ---------------------------------------------------------------------------
// Kernel 2: pure-compute attention. 1024 blocks = (b, h, row-half), 256 thr.
// Prologue: 1 scalar cnt load, 2 coalesced K/V float4 loads -> LDS, 8 q loads,
// ONE barrier. Thread t: chunk c=t&7 (L = ceil(Nk/8) keys, slot s=8j+c),
// rows rh*256 + 8g + 0..7 (g=t>>3) as 4 packed pairs. No-max softmax
// (exact, verified r1-r7); zero pad slots give e=1, removed via lcorr=8L-Nk.
// Octet butterfly merges chunks; lane c writes row 8g+c scaled 1/l.
// ---------------------------------------------------------------------------
__global__ __launch_bounds__(256) void attn_kernel(
    const float4* __restrict__ qc, const float4* __restrict__ kc,
    const float4* __restrict__ vc, const unsigned short* __restrict__ rlist,
    const int* __restrict__ cnt, float* __restrict__ att)
{
    const int blk = blockIdx.x;
    const int b   = blk >> 3;
    const int h   = (blk >> 1) & 3;
    const int rh  = blk & 1;
    const int t   = threadIdx.x;
    const int c   = t & 7;
    const int g   = t >> 3;

    const int Nk = cnt[b];
    if (rh * 256 >= Nk) return;                 // uniform early exit
    const int L  = (Nk + 7) >> 3;
    const int L8 = L << 3;
    const float lcorr = (float)(L8 - Nk);       // zero-pad slots give e=1

    __shared__ float4 sk[CH * CPAD];
    __shared__ float4 sv[CH * CPAD];

    const float4* kcb = kc + (size_t)(b * NH + h) * NE;
    const float4* vcb = vc + (size_t)(b * NH + h) * NE;
    #pragma unroll
    for (int s0 = 0; s0 < 2; ++s0) {
        const int s = t + s0 * 256;
        if (s < L8) {
            sk[(s & 7) * CPAD + (s >> 3)] = kcb[s];
            sv[(s & 7) * CPAD + (s >> 3)] = vcb[s];
        }
    }

    // q for 8 row-slots (coalesced-ish 16B loads from L2)
    const float4* qcb = qc + (size_t)(b * NH + h) * NE;
    const float4 z4 = make_float4(0.f, 0.f, 0.f, 0.f);
    float4 qa[8];
    #pragma unroll
    for (int r = 0; r < 8; ++r) {
        const int slot = rh * 256 + 8 * g + r;
        qa[r] = (slot < Nk) ? qcb[slot] : z4;
    }

    __syncthreads();

    v2f qv[4][DPH];
    #pragma unroll
    for (int p = 0; p < 4; ++p) {
        qv[p][0] = (v2f){qa[2*p].x, qa[2*p+1].x};
        qv[p][1] = (v2f){qa[2*p].y, qa[2*p+1].y};
        qv[p][2] = (v2f){qa[2*p].z, qa[2*p+1].z};
        qv[p][3] = (v2f){qa[2*p].w, qa[2*p+1].w};
    }

    const float4* kb = sk + c * CPAD;
    const float4* vb = sv + c * CPAD;
    v2f l2[4], a2[4][DPH];
    #pragma unroll
    for (int p = 0; p < 4; ++p) {
        l2[p] = (v2f)(0.f);
        #pragma unroll
        for (int d = 0; d < DPH; ++d) a2[p][d] = (v2f)(0.f);
    }

    #pragma unroll 4
    for (int j = 0; j < L; ++j) {
        const float4 kv = kb[j];
        const float4 uv = vb[j];
        const v2f kx = (v2f){kv.x, kv.x}, ky = (v2f){kv.y, kv.y},
                  kz = (v2f){kv.z, kv.z}, kw = (v2f){kv.w, kv.w};
        const v2f ux = (v2f){uv.x, uv.x}, uy = (v2f){uv.y, uv.y},
                  uz = (v2f){uv.z, uv.z}, uw = (v2f){uv.w, uv.w};
        #pragma unroll
        for (int p = 0; p < 4; ++p) {
            v2f s = qv[p][3] * kw;
            s = __builtin_elementwise_fma(qv[p][2], kz, s);
            s = __builtin_elementwise_fma(qv[p][1], ky, s);
            s = __builtin_elementwise_fma(qv[p][0], kx, s);
            v2f e;
            e.x = EXP2(s.x);
            e.y = EXP2(s.y);
            l2[p] += e;
            a2[p][0] = __builtin_elementwise_fma(e, ux, a2[p][0]);
            a2[p][1] = __builtin_elementwise_fma(e, uy, a2[p][1]);
            a2[p][2] = __builtin_elementwise_fma(e, uz, a2[p][2]);
            a2[p][3] = __builtin_elementwise_fma(e, uw, a2[p][3]);
        }
    }

    // butterfly over the c-octet (combine 8 chunks)
    #pragma unroll
    for (int m = 1; m <= 4; m <<= 1) {
        #pragma unroll
        for (int p = 0; p < 4; ++p) {
            l2[p].x += __shfl_xor(l2[p].x, m);
            l2[p].y += __shfl_xor(l2[p].y, m);
            #pragma unroll
            for (int d = 0; d < DPH; ++d) {
                a2[p][d].x += __shfl_xor(a2[p][d].x, m);
                a2[p][d].y += __shfl_xor(a2[p][d].y, m);
            }
        }
    }

    // lane c takes row-slot 8g + c (static unroll, no dynamic reg indexing)
    float lsel = l2[0].x, p0 = a2[0][0].x, p1 = a2[0][1].x,
          p2 = a2[0][2].x, p3 = a2[0][3].x;
    #pragma unroll
    for (int r = 1; r < 8; ++r) {
        if (r == c) {
            const int pp = r >> 1;
            if (r & 1) {
                lsel = l2[pp].y; p0 = a2[pp][0].y; p1 = a2[pp][1].y;
                p2 = a2[pp][2].y; p3 = a2[pp][3].y;
            } else {
                lsel = l2[pp].x; p0 = a2[pp][0].x; p1 = a2[pp][1].x;
                p2 = a2[pp][2].x; p3 = a2[pp][3].x;
            }
        }
    }

    const int slot = rh * 256 + 8 * g + c;
    if (slot < Nk) {
        const int row = rlist[b * NE + slot];   // active row: mask = 1
        const float rs = 1.0f / (lsel - lcorr);
        float4* o = (float4*)(att + ((size_t)(b * NE + row)) * NEMBD + h * DPH);
        *o = make_float4(p0 * rs, p1 * rs, p2 * rs, p3 * rs);
    }
}

// ---------------------------------------------------------------------------
// Kernel 3: epilogue (unchanged, verified r6-r7). Masked rows' att was never
// written (0xAA poison ~ -3e-13, finite) -> zeroed via *mi.
// ---------------------------------------------------------------------------
__global__ __launch_bounds__(NE) void epi_kernel(
    const float* __restrict__ inp, const float* __restrict__ mask,
    const float* __restrict__ Wpost, const float* __restrict__ att,
    float* __restrict__ out)
{
    const int b = blockIdx.x;
    const int i = threadIdx.x;
    const int wave = i >> 6;
    const int lane = i & 63;

    __shared__ float swp[F * NEMBD];
    __shared__ float red[64];

    if (i < F * NEMBD) swp[i] = Wpost[i];
    __syncthreads();

    const float mi = mask[b * NE + i];
    const float* row = inp + ((size_t)(b * NE + i)) * F;
    const float* ar  = att + ((size_t)(b * NE + i)) * NEMBD;

    float a[NEMBD];
    #pragma unroll
    for (int t = 0; t < NEMBD; t += 4) {
        const float4 v = *(const float4*)(ar + t);
        a[t] = v.x * mi; a[t+1] = v.y * mi; a[t+2] = v.z * mi; a[t+3] = v.w * mi;
    }

    float x[F];
    #pragma unroll
    for (int f = 0; f < F; ++f) {
        float acc = row[f] * mi;
        #pragma unroll
        for (int t = 0; t < NEMBD; ++t) acc = fmaf(a[t], swp[f * NEMBD + t], acc);
        x[f] = acc;
    }

    float rsum = x[0] + x[1] + x[2] + x[3] + x[4] + x[5];
    float rn = mi;
    #pragma unroll
    for (int off = 32; off >= 1; off >>= 1) {
        rsum += __shfl_down(rsum, off);
        rn   += __shfl_down(rn, off);
    }
    if (lane == 0) { red[wave * 2] = rsum; red[wave * 2 + 1] = rn; }
    __syncthreads();
    float S = 0.f, N = 0.f;
    #pragma unroll
    for (int w = 0; w < 8; ++w) { S += red[w * 2]; N += red[w * 2 + 1]; }

    const float mu     = S / (6.0f * N);
    const float sum_x2 = S + (NE - N) * 6.0f * mu;
    const float m2     = sum_x2 / (NE * 6.0f);
    const float add    = (1.0f - mi) * mu;

    float ss = 0.f;
    #pragma unroll
    for (int f = 0; f < F; ++f) { const float d = x[f] + add - m2; ss = fmaf(d, d, ss); }

    __syncthreads();
    #pragma unroll
    for (int off = 32; off >= 1; off >>= 1) ss += __shfl_down(ss, off);
    if (lane == 0) red[wave] = ss;
    __syncthreads();
    float vs = 0.f;
    #pragma unroll
    for (int w = 0; w < 8; ++w) vs += red[w];

    const float var  = vs / (NE * 6.0f - 1.0f);
    const float stdv = sqrtf(var) * sqrtf((6.0f * NE - 1.0f) / (6.0f * N - 1.0f));
    const float inv  = 1.0f / (stdv + 1e-6f);

    float y[F];
    #pragma unroll
    for (int f = 0; f < F; ++f) y[f] = mi * (x[f] - mu) * inv;

    __syncthreads();
    #pragma unroll
    for (int off = 32; off >= 1; off >>= 1) {
        #pragma unroll
        for (int f = 0; f < F; ++f) y[f] += __shfl_down(y[f], off);
    }
    if (lane == 0) {
        #pragma unroll
        for (int f = 0; f < F; ++f) red[wave * F + f] = y[f];
    }
    __syncthreads();
    if (i < F) {
        float tt = 0.f;
        #pragma unroll
        for (int w = 0; w < 8; ++w) tt += red[w * F + i];
        out[b * F + i] = tt / N;
    }
}

// ---------------------------------------------------------------------------
extern "C" void kernel_launch(void* const* d_in, const int* in_sizes, int n_in,
                              void* d_out, int out_size, void* d_ws, size_t ws_size,
                              hipStream_t stream) {
    const float* inp   = (const float*)d_in[0];
    const float* mask  = (const float*)d_in[1];
    const float* Wq    = (const float*)d_in[2];
    const float* Wk    = (const float*)d_in[3];
    const float* Wv    = (const float*)d_in[4];
    const float* Wpost = (const float*)d_in[5];
    float* out = (float*)d_out;

    char* ws = (char*)d_ws;
    const size_t SZQKV = (size_t)BS * NH * NE * sizeof(float4);  // 4 MB each
    float4* qc = (float4*)(ws);
    float4* kc = (float4*)(ws + SZQKV);
    float4* vc = (float4*)(ws + 2 * SZQKV);
    float*  att = (float*)(ws + 3 * SZQKV);                      // 4 MB
    unsigned short* rlist = (unsigned short*)(ws + 4 * SZQKV);   // 128 KB
    int* cnt = (int*)(ws + 4 * SZQKV + (size_t)BS * NE * sizeof(unsigned short));

    qkv_kernel <<<BS, NE, 0, stream>>>(inp, mask, Wq, Wk, Wv, qc, kc, vc, rlist, cnt);
    attn_kernel<<<BS * NH * 2, 256, 0, stream>>>(qc, kc, vc, rlist, cnt, att);
    epi_kernel <<<BS, NE, 0, stream>>>(inp, mask, Wpost, att, out);
}

// Round 9
// 94.189 us; speedup vs baseline: 1.1607x; 1.1607x over previous
//
#include <hip/hip_runtime.h>
#include <math.h>

#define BS    128
#define NE    512
#define F     6
#define NH    4
#define DPH   4
#define NEMBD 16

#define CH    8
#define CPAD  65   // float4 stride per chunk; 8 broadcast addrs/wave, conflict-free (r2-r8)

#if __has_builtin(__builtin_amdgcn_exp2f)
#define EXP2(x) __builtin_amdgcn_exp2f(x)
#else
#define EXP2(x) exp2f(x)
#endif

typedef float v2f __attribute__((ext_vector_type(2)));

// ---------------------------------------------------------------------------
// attention (r6 base, best measured): 512 blocks = (b,h), 512 threads.
// Deterministic mask-compaction (ballot + wave-count scan); slot s dealt
// round-robin to chunk s&7 index s>>3 -> inner loop L = ceil(Nk/8) iters.
// Masked entities skipped (keys AND rows); zero-pad tail slots contribute
// e=exp2(0)=1, removed exactly via lcorr = 8L - Nk. No-max softmax
// (exact, verified r1-r8). q computed once per row into LDS.
// NEW (r9): reduce-scatter butterfly -- each xor step sends only the rows
// the partner still owns (35 shfls vs 120) and ends with lane c holding
// exactly row 8g+c (no select tree). Same pairing tree -> bit-identical.
// ---------------------------------------------------------------------------
__global__ __launch_bounds__(512) void attn_kernel(
    const float* __restrict__ inp, const float* __restrict__ mask,
    const float* __restrict__ Wq, const float* __restrict__ Wk,
    const float* __restrict__ Wv, float* __restrict__ att_out)
{
    const int b    = blockIdx.x >> 2;
    const int h    = blockIdx.x & 3;
    const int t    = threadIdx.x;
    const int c    = t & 7;
    const int g    = t >> 3;
    const int w    = t >> 6;
    const int lane = t & 63;

    __shared__ float4 sk[CH * CPAD];
    __shared__ float4 sv[CH * CPAD];
    __shared__ float4 sq[576];            // row-slot s at sq[9*(s>>3) + (s&7)]
    __shared__ unsigned short rlist[512]; // compacted slot -> entity id
    __shared__ int wcnt[8];               // per-wave active counts

    // ---- zero pass: thread t zeroes slot-position t in sk/sv/sq ----
    const float4 z4 = make_float4(0.f, 0.f, 0.f, 0.f);
    sk[c * CPAD + g] = z4;
    sv[c * CPAD + g] = z4;
    sq[9 * g + c]    = z4;

    const float me = mask[b * NE + t];
    const bool act = me > 0.f;            // mask is exactly 0.0 or 1.0

    // ---- deterministic compaction index (ballot + wave-count scan) ----
    const unsigned long long ball = __ballot(act);
    const int prefix = __builtin_amdgcn_mbcnt_hi((unsigned int)(ball >> 32),
                        __builtin_amdgcn_mbcnt_lo((unsigned int)ball, 0));
    if (lane == 0) wcnt[w] = (int)__popcll(ball);

    __syncthreads();   // B1: zeros + wcnt visible

    int base = 0, Nk = 0;
    #pragma unroll
    for (int u = 0; u < 8; ++u) {
        const int cu = wcnt[u];
        Nk += cu;
        if (u < w) base += cu;
    }
    const int L = (Nk + 7) >> 3;              // keys per chunk
    const float lcorr = (float)(8 * L - Nk);  // zero-pad slots give e=1

    // ---- staging: active thread computes K/V/Q for its entity -> slot s ----
    if (act) {
        const int s = base + prefix;
        const float2* rp = (const float2*)(inp + ((size_t)(b * NE + t)) * F);
        const float2 r0 = rp[0], r1 = rp[1], r2 = rp[2];
        const float x0 = r0.x, x1 = r0.y, x2 = r1.x,
                    x3 = r1.y, x4 = r2.x, x5 = r2.y;   // mask=1: no scaling
        const float* wk = Wk + h * DPH * F;
        const float* wv = Wv + h * DPH * F;
        const float* wq = Wq + h * DPH * F;
        const float QS = 0.5f * 1.44269504088896340736f;  // 1/sqrt(4)*log2(e)
        float kk[4], vv[4], qq[4];
        #pragma unroll
        for (int d = 0; d < DPH; ++d) {
            const float* wd = wk + d * F;
            kk[d] = x0*wd[0] + x1*wd[1] + x2*wd[2] + x3*wd[3] + x4*wd[4] + x5*wd[5];
            wd = wv + d * F;
            vv[d] = x0*wd[0] + x1*wd[1] + x2*wd[2] + x3*wd[3] + x4*wd[4] + x5*wd[5];
            wd = wq + d * F;
            qq[d] = QS * (x0*wd[0] + x1*wd[1] + x2*wd[2] + x3*wd[3] + x4*wd[4] + x5*wd[5]);
        }
        sk[(s & 7) * CPAD + (s >> 3)] = make_float4(kk[0], kk[1], kk[2], kk[3]);
        sv[(s & 7) * CPAD + (s >> 3)] = make_float4(vv[0], vv[1], vv[2], vv[3]);
        sq[9 * (s >> 3) + (s & 7)]    = make_float4(qq[0], qq[1], qq[2], qq[3]);
        rlist[s] = (unsigned short)t;
    }

    __syncthreads();   // B2: sk/sv/sq/rlist visible

    // ---- wave-granular row skip: wave w owns row-slots [64w, 64w+64) ----
    if (64 * w >= Nk) return;

    // ---- load q for row-slots 8g..8g+7 (broadcast b128, conflict-free) ----
    float4 qa[8];
    #pragma unroll
    for (int r = 0; r < 8; ++r) qa[r] = sq[9 * g + r];
    v2f qv[4][DPH];
    #pragma unroll
    for (int p = 0; p < 4; ++p) {
        qv[p][0] = (v2f){qa[2*p].x, qa[2*p+1].x};
        qv[p][1] = (v2f){qa[2*p].y, qa[2*p+1].y};
        qv[p][2] = (v2f){qa[2*p].z, qa[2*p+1].z};
        qv[p][3] = (v2f){qa[2*p].w, qa[2*p+1].w};
    }

    // ---- inner loop: L keys of chunk c x 4 packed row pairs ----
    const float4* kb = sk + c * CPAD;
    const float4* vb = sv + c * CPAD;
    v2f l2[4], a2[4][DPH];
    #pragma unroll
    for (int p = 0; p < 4; ++p) {
        l2[p] = (v2f)(0.f);
        #pragma unroll
        for (int d = 0; d < DPH; ++d) a2[p][d] = (v2f)(0.f);
    }

    #pragma unroll 4
    for (int j = 0; j < L; ++j) {
        const float4 kv = kb[j];
        const float4 uv = vb[j];
        const v2f kx = (v2f){kv.x, kv.x}, ky = (v2f){kv.y, kv.y},
                  kz = (v2f){kv.z, kv.z}, kw = (v2f){kv.w, kv.w};
        const v2f ux = (v2f){uv.x, uv.x}, uy = (v2f){uv.y, uv.y},
                  uz = (v2f){uv.z, uv.z}, uw = (v2f){uv.w, uv.w};
        #pragma unroll
        for (int p = 0; p < 4; ++p) {
            v2f s = qv[p][3] * kw;
            s = __builtin_elementwise_fma(qv[p][2], kz, s);
            s = __builtin_elementwise_fma(qv[p][1], ky, s);
            s = __builtin_elementwise_fma(qv[p][0], kx, s);
            v2f e;
            e.x = EXP2(s.x);
            e.y = EXP2(s.y);
            l2[p] += e;
            a2[p][0] = __builtin_elementwise_fma(e, ux, a2[p][0]);
            a2[p][1] = __builtin_elementwise_fma(e, uy, a2[p][1]);
            a2[p][2] = __builtin_elementwise_fma(e, uz, a2[p][2]);
            a2[p][3] = __builtin_elementwise_fma(e, uw, a2[p][3]);
        }
    }

    // ---- reduce-scatter butterfly over the c-octet ---------------------
    // step 1 (xor 1): keep row-parity b0 of each pair; partner sends the
    // row I keep. Same pairing tree as the old full butterfly -> identical fp.
    const int b0 = c & 1, b1 = (c >> 1) & 1, b2 = (c >> 2) & 1;

    float k1[5][4];   // [val: 0=l, 1..4=a[d]][pair p] -> row 2p + b0
    #pragma unroll
    for (int p = 0; p < 4; ++p) {
        {
            const v2f v = l2[p];
            const float snd = b0 ? v.x : v.y;
            k1[0][p] = (b0 ? v.y : v.x) + __shfl_xor(snd, 1);
        }
        #pragma unroll
        for (int d = 0; d < DPH; ++d) {
            const v2f v = a2[p][d];
            const float snd = b0 ? v.x : v.y;
            k1[1 + d][p] = (b0 ? v.y : v.x) + __shfl_xor(snd, 1);
        }
    }

    // step 2 (xor 2): keep pairs p with (p&1)==b1 -> rows 4q + 2b1 + b0
    float k2[5][2];
    #pragma unroll
    for (int v = 0; v < 5; ++v) {
        #pragma unroll
        for (int q = 0; q < 2; ++q) {
            const float keep = b1 ? k1[v][2*q + 1] : k1[v][2*q];
            const float snd  = b1 ? k1[v][2*q]     : k1[v][2*q + 1];
            k2[v][q] = keep + __shfl_xor(snd, 2);
        }
    }

    // step 3 (xor 4): keep q==b2 -> final row = 4b2 + 2b1 + b0 = c
    float fin[5];
    #pragma unroll
    for (int v = 0; v < 5; ++v) {
        const float keep = b2 ? k2[v][1] : k2[v][0];
        const float snd  = b2 ? k2[v][0] : k2[v][1];
        fin[v] = keep + __shfl_xor(snd, 4);
    }

    const int slot = 8 * g + c;
    if (slot < Nk) {
        const int row = rlist[slot];          // active row: mask = 1
        const float rs = 1.0f / (fin[0] - lcorr);
        float4* o = (float4*)(att_out + ((size_t)(b * NE + row)) * NEMBD + h * DPH);
        *o = make_float4(fin[1] * rs, fin[2] * rs, fin[3] * rs, fin[4] * rs);
    }
}

// ---------------------------------------------------------------------------
// epilogue: post-proj + residual + mask-corrected norm + masked mean pool.
// att rows of masked entities are never written (poison) -> zeroed via *mi.
// Verified r6-r8.
// ---------------------------------------------------------------------------
__global__ __launch_bounds__(NE) void epi_kernel(
    const float* __restrict__ inp, const float* __restrict__ mask,
    const float* __restrict__ Wpost, const float* __restrict__ att,
    float* __restrict__ out)
{
    const int b = blockIdx.x;
    const int i = threadIdx.x;
    const int wave = i >> 6;
    const int lane = i & 63;

    __shared__ float swp[F * NEMBD];
    __shared__ float red[64];

    if (i < F * NEMBD) swp[i] = Wpost[i];
    __syncthreads();

    const float mi = mask[b * NE + i];
    const float* row = inp + ((size_t)(b * NE + i)) * F;
    const float* ar  = att + ((size_t)(b * NE + i)) * NEMBD;

    float a[NEMBD];
    #pragma unroll
    for (int t = 0; t < NEMBD; t += 4) {
        const float4 v = *(const float4*)(ar + t);
        a[t] = v.x * mi; a[t+1] = v.y * mi; a[t+2] = v.z * mi; a[t+3] = v.w * mi;
    }

    float x[F];
    #pragma unroll
    for (int f = 0; f < F; ++f) {
        float acc = row[f] * mi;
        #pragma unroll
        for (int t = 0; t < NEMBD; ++t) acc = fmaf(a[t], swp[f * NEMBD + t], acc);
        x[f] = acc;
    }

    // ---- phase 1: S = sum(x), N = sum(mask) ----
    float rsum = x[0] + x[1] + x[2] + x[3] + x[4] + x[5];
    float rn = mi;
    #pragma unroll
    for (int off = 32; off >= 1; off >>= 1) {
        rsum += __shfl_down(rsum, off);
        rn   += __shfl_down(rn, off);
    }
    if (lane == 0) { red[wave * 2] = rsum; red[wave * 2 + 1] = rn; }
    __syncthreads();
    float S = 0.f, N = 0.f;
    #pragma unroll
    for (int w = 0; w < 8; ++w) { S += red[w * 2]; N += red[w * 2 + 1]; }

    const float mu     = S / (6.0f * N);
    const float sum_x2 = S + (NE - N) * 6.0f * mu;
    const float m2     = sum_x2 / (NE * 6.0f);
    const float add    = (1.0f - mi) * mu;

    float ss = 0.f;
    #pragma unroll
    for (int f = 0; f < F; ++f) { const float d = x[f] + add - m2; ss = fmaf(d, d, ss); }

    // ---- phase 2: sum of squares ----
    __syncthreads();
    #pragma unroll
    for (int off = 32; off >= 1; off >>= 1) ss += __shfl_down(ss, off);
    if (lane == 0) red[wave] = ss;
    __syncthreads();
    float vs = 0.f;
    #pragma unroll
    for (int w = 0; w < 8; ++w) vs += red[w];

    const float var  = vs / (NE * 6.0f - 1.0f);
    const float stdv = sqrtf(var) * sqrtf((6.0f * NE - 1.0f) / (6.0f * N - 1.0f));
    const float inv  = 1.0f / (stdv + 1e-6f);

    float y[F];
    #pragma unroll
    for (int f = 0; f < F; ++f) y[f] = mi * (x[f] - mu) * inv;

    // ---- phase 3: 6 masked feature sums ----
    __syncthreads();
    #pragma unroll
    for (int off = 32; off >= 1; off >>= 1) {
        #pragma unroll
        for (int f = 0; f < F; ++f) y[f] += __shfl_down(y[f], off);
    }
    if (lane == 0) {
        #pragma unroll
        for (int f = 0; f < F; ++f) red[wave * F + f] = y[f];
    }
    __syncthreads();
    if (i < F) {
        float tt = 0.f;
        #pragma unroll
        for (int w = 0; w < 8; ++w) tt += red[w * F + i];
        out[b * F + i] = tt / N;
    }
}

// ---------------------------------------------------------------------------
extern "C" void kernel_launch(void* const* d_in, const int* in_sizes, int n_in,
                              void* d_out, int out_size, void* d_ws, size_t ws_size,
                              hipStream_t stream) {
    const float* inp   = (const float*)d_in[0];
    const float* mask  = (const float*)d_in[1];
    const float* Wq    = (const float*)d_in[2];
    const float* Wk    = (const float*)d_in[3];
    const float* Wv    = (const float*)d_in[4];
    const float* Wpost = (const float*)d_in[5];
    float* out = (float*)d_out;
    float* att = (float*)d_ws;   // BS*NE*NEMBD floats = 4 MB

    attn_kernel<<<BS * NH, 512, 0, stream>>>(inp, mask, Wq, Wk, Wv, att);
    epi_kernel <<<BS, NE, 0, stream>>>(inp, mask, Wpost, att, out);
}